// Round 12
// baseline (152.945 us; speedup 1.0000x reference)
//
#include <hip/hip_runtime.h>
#include <hip/hip_bf16.h>

typedef __bf16 bf16x8 __attribute__((ext_vector_type(8)));
typedef float f32x4 __attribute__((ext_vector_type(4)));
typedef float f32x16 __attribute__((ext_vector_type(16)));
using u16 = unsigned short;
using u32 = unsigned int;

#define LDSS 72  // padded LDS row stride in bf16 elems
#define TILE (64 * LDSS)
#define LOG2E 1.4426950408889634f

__device__ __forceinline__ u16 f2bf(float f) {
  union { float f; u32 u; } v; v.f = f;
  u32 r = v.u + 0x7fffu + ((v.u >> 16) & 1u);   // RNE
  return (u16)(r >> 16);
}

__device__ __forceinline__ u32 cvt_pk_bf16(float lo, float hi) {
  u32 r;
  asm("v_cvt_pk_bf16_f32 %0, %1, %2" : "=v"(r) : "v"(lo), "v"(hi));
  return r;
}

__device__ __forceinline__ float exp2_fast(float x) {
  float r;
  asm("v_exp_f32 %0, %1" : "=v"(r) : "v"(x));
  return r;
}

// ---------------- cast kernels ----------------
__global__ void cast_x_kernel(const float* __restrict__ x, u16* __restrict__ xb) {
  int i = (blockIdx.x * 256 + threadIdx.x) * 8;
  float4 f0 = *(const float4*)&x[i];
  float4 f1 = *(const float4*)&x[i + 4];
  u16 u[8];
  u[0] = f2bf(f0.x); u[1] = f2bf(f0.y); u[2] = f2bf(f0.z); u[3] = f2bf(f0.w);
  u[4] = f2bf(f1.x); u[5] = f2bf(f1.y); u[6] = f2bf(f1.z); u[7] = f2bf(f1.w);
  *(uint4*)&xb[i] = *(uint4*)u;
}

// weights (512x512, stored (in,out)) -> bf16 transposed (out,in), LDS-tiled.
__global__ __launch_bounds__(256) void cast_wT_kernel(
    const float* __restrict__ w0, const float* __restrict__ w1,
    const float* __restrict__ w2, const float* __restrict__ w3,
    u16* __restrict__ t0, u16* __restrict__ t1,
    u16* __restrict__ t2, u16* __restrict__ t3) {
  __shared__ u16 tl[64][72];
  int wi = blockIdx.z;
  const float* w; u16* t;
  if (wi == 0)      { w = w0; t = t0; }
  else if (wi == 1) { w = w1; t = t1; }
  else if (wi == 2) { w = w2; t = t2; }
  else              { w = w3; t = t3; }
  int r0 = blockIdx.x * 64, c0 = blockIdx.y * 64;
  int tid = threadIdx.x;
  int row = tid >> 2, q = tid & 3;
#pragma unroll
  for (int j = 0; j < 4; j++) {
    float4 f = *(const float4*)&w[(r0 + row) * 512 + c0 + q * 16 + j * 4];
    tl[row][q * 16 + j * 4 + 0] = f2bf(f.x);
    tl[row][q * 16 + j * 4 + 1] = f2bf(f.y);
    tl[row][q * 16 + j * 4 + 2] = f2bf(f.z);
    tl[row][q * 16 + j * 4 + 3] = f2bf(f.w);
  }
  __syncthreads();
  int crow = tid >> 2;
  u16 tmp[16];
#pragma unroll
  for (int j = 0; j < 16; j++) tmp[j] = tl[q * 16 + j][crow];
  *(uint4*)&t[(c0 + crow) * 512 + r0 + q * 16]     = *(uint4*)&tmp[0];
  *(uint4*)&t[(c0 + crow) * 512 + r0 + q * 16 + 8] = *(uint4*)&tmp[8];
}

// ---------------- QKV projection GEMM: 64x64 tile, reg-prefetch ----------------
__global__ __launch_bounds__(256) void proj_kernel(
    const u16* __restrict__ xb,
    const u16* __restrict__ wqT, const u16* __restrict__ wkT, const u16* __restrict__ wvT,
    const float* __restrict__ bq, const float* __restrict__ bk, const float* __restrict__ bv,
    u16* __restrict__ Q, u16* __restrict__ K, u16* __restrict__ Vt) {
  __shared__ u16 Alds[64 * LDSS];
  __shared__ u16 Blds[64 * LDSS];
  int which = blockIdx.z;
  const u16* wT; const float* bias; u16* out;
  if (which == 0)      { wT = wqT; bias = bq; out = Q; }
  else if (which == 1) { wT = wkT; bias = bk; out = K; }
  else                 { wT = wvT; bias = bv; out = Vt; }

  int m0 = blockIdx.y * 64;
  int n0 = blockIdx.x * 64;
  int tid = threadIdx.x;
  int lane = tid & 63, w = tid >> 6;
  int wm = w >> 1, wn = w & 1;
  int l15 = lane & 15, l4 = lane >> 4;

  int r0 = tid >> 3, c8 = (tid & 7) * 8;

  uint4 ar0 = *(const uint4*)&xb[(m0 + r0) * 512 + c8];
  uint4 ar1 = *(const uint4*)&xb[(m0 + r0 + 32) * 512 + c8];
  uint4 br0 = *(const uint4*)&wT[(n0 + r0) * 512 + c8];
  uint4 br1 = *(const uint4*)&wT[(n0 + r0 + 32) * 512 + c8];

  f32x4 acc[2][2] = {};
  for (int ks = 0; ks < 8; ks++) {
    __syncthreads();
    *(uint4*)&Alds[r0 * LDSS + c8]        = ar0;
    *(uint4*)&Alds[(r0 + 32) * LDSS + c8] = ar1;
    *(uint4*)&Blds[r0 * LDSS + c8]        = br0;
    *(uint4*)&Blds[(r0 + 32) * LDSS + c8] = br1;
    __syncthreads();
    if (ks < 7) {
      int k0 = (ks + 1) * 64;
      ar0 = *(const uint4*)&xb[(m0 + r0) * 512 + k0 + c8];
      ar1 = *(const uint4*)&xb[(m0 + r0 + 32) * 512 + k0 + c8];
      br0 = *(const uint4*)&wT[(n0 + r0) * 512 + k0 + c8];
      br1 = *(const uint4*)&wT[(n0 + r0 + 32) * 512 + k0 + c8];
    }
#pragma unroll
    for (int kk = 0; kk < 2; kk++) {
      bf16x8 a[2], b[2];
#pragma unroll
      for (int f = 0; f < 2; f++) {
        a[f] = *(const bf16x8*)&Alds[(wm * 32 + f * 16 + l15) * LDSS + kk * 32 + l4 * 8];
        b[f] = *(const bf16x8*)&Blds[(wn * 32 + f * 16 + l15) * LDSS + kk * 32 + l4 * 8];
      }
#pragma unroll
      for (int fm = 0; fm < 2; fm++)
#pragma unroll
        for (int fn = 0; fn < 2; fn++) {
          if (which == 2)
            acc[fm][fn] = __builtin_amdgcn_mfma_f32_16x16x32_bf16(b[fn], a[fm], acc[fm][fn], 0, 0, 0);
          else
            acc[fm][fn] = __builtin_amdgcn_mfma_f32_16x16x32_bf16(a[fm], b[fn], acc[fm][fn], 0, 0, 0);
        }
    }
  }
  int bidx = m0 >> 11;
  int head = n0 >> 6;
  if (which == 2) {
#pragma unroll
    for (int fm = 0; fm < 2; fm++)
#pragma unroll
      for (int fn = 0; fn < 2; fn++)
#pragma unroll
        for (int r = 0; r < 4; r++) {
          int drow = wn * 32 + fn * 16 + l4 * 4 + r;
          int col  = wm * 32 + fm * 16 + l15;
          float vv = acc[fm][fn][r] + bias[n0 + drow];
          out[((size_t)(bidx * 8 + head) * 64 + drow) * 2048 + (m0 & 2047) + col] = f2bf(vv);
        }
  } else {
#pragma unroll
    for (int fm = 0; fm < 2; fm++)
#pragma unroll
      for (int fn = 0; fn < 2; fn++)
#pragma unroll
        for (int r = 0; r < 4; r++) {
          int row = wm * 32 + fm * 16 + l4 * 4 + r;
          int col = wn * 32 + fn * 16 + l15;
          int nrow = (m0 & 2047) + row;
          float vv = acc[fm][fn][r] + bias[n0 + col];
          out[(((size_t)(bidx * 8 + head) * 2048) + nrow) * 64 + col] = f2bf(vv);
        }
  }
}

// ---------------- flash attention: KV-split x2, full bias prefetch ----------------
// 8 waves: group g2=w>>2 does KV tiles g2*16..g2*16+15; qtile 128; LDS merge.
// grid 512 x 512thr -> 2 blocks/CU = 16 waves/CU (4/SIMD).
__global__ __launch_bounds__(512, 2) void attn_kernel(
    const u16* __restrict__ Q, const u16* __restrict__ K, const u16* __restrict__ Vt,
    const float* __restrict__ bias, u16* __restrict__ O) {
  __shared__ u16 smem[4 * TILE];   // 36864 B: K[2] then Vt[2]; reused for merge

  int qt = blockIdx.x, h = blockIdx.y, b = blockIdx.z;
  int tid = threadIdx.x;
  int lane = tid & 63, w = tid >> 6;       // w 0..7
  int g2 = w >> 2, ww = w & 3;             // group, wave-within-group
  int l31 = lane & 31, hi = lane >> 5;
  int qrow = qt * 128 + ww * 32 + l31;

  const u16* Qbh  = Q  + (size_t)(b * 8 + h) * 2048 * 64;
  const u16* Kbh  = K  + (size_t)(b * 8 + h) * 2048 * 64;
  const u16* Vtbh = Vt + (size_t)(b * 8 + h) * 64 * 2048;
  const float* biasq = bias + (size_t)b * 2048 * 2048 + (size_t)qrow * 2048;

  u16* Kl = smem + g2 * TILE;
  u16* Vl = smem + (2 + g2) * TILE;
  const int tbase = g2 * 16;               // first KV tile for this group

  bf16x8 qf[4];
#pragma unroll
  for (int dk = 0; dk < 4; dk++)
    qf[dk] = *(const bf16x8*)&Qbh[qrow * 64 + dk * 16 + hi * 8];

  f32x16 o[2] = {};
  float mrow = -1e30f, lrow = 0.f;

  // staging: 256 thr per group; rows r0, r0+32; col chunk c8
  int tid2 = tid & 255;
  int r0 = tid2 >> 3, c8 = (tid2 & 7) * 8;

  // prologue: prefetch first tile + FULL bias tile (both kt halves)
  uint4 kr0 = *(const uint4*)&Kbh[(tbase * 64 + r0) * 64 + c8];
  uint4 kr1 = *(const uint4*)&Kbh[(tbase * 64 + r0 + 32) * 64 + c8];
  uint4 vr0 = *(const uint4*)&Vtbh[r0 * 2048 + tbase * 64 + c8];
  uint4 vr1 = *(const uint4*)&Vtbh[(r0 + 32) * 2048 + tbase * 64 + c8];
  float4 bb[8];
#pragma unroll
  for (int kt = 0; kt < 2; kt++)
#pragma unroll
    for (int g = 0; g < 4; g++)
      bb[kt * 4 + g] = *(const float4*)&biasq[tbase * 64 + kt * 32 + 8 * g + 4 * hi];

  for (int t = 0; t < 16; t++) {
    __syncthreads();   // (A) prev compute done
    *(uint4*)&Kl[r0 * LDSS + c8]        = kr0;
    *(uint4*)&Kl[(r0 + 32) * LDSS + c8] = kr1;
    *(uint4*)&Vl[r0 * LDSS + c8]        = vr0;
    *(uint4*)&Vl[(r0 + 32) * LDSS + c8] = vr1;
    __syncthreads();   // (B) staging visible

    int tile = tbase + t;
    bool pf = (t < 15);

    // S^T = K·Q^T (two 32x32 k-tiles)
    f32x16 s[2] = {};
    __builtin_amdgcn_s_setprio(1);
#pragma unroll
    for (int dk = 0; dk < 4; dk++) {
      bf16x8 a0 = *(const bf16x8*)&Kl[l31 * LDSS + dk * 16 + hi * 8];
      s[0] = __builtin_amdgcn_mfma_f32_32x32x16_bf16(a0, qf[dk], s[0], 0, 0, 0);
      bf16x8 a1 = *(const bf16x8*)&Kl[(32 + l31) * LDSS + dk * 16 + hi * 8];
      s[1] = __builtin_amdgcn_mfma_f32_32x32x16_bf16(a1, qf[dk], s[1], 0, 0, 0);
    }
    __builtin_amdgcn_s_setprio(0);

    // scale + bias, pairwise max tree
    float mx[8];
#pragma unroll
    for (int kt = 0; kt < 2; kt++)
#pragma unroll
      for (int g = 0; g < 4; g++) {
        float4 bv4 = bb[kt * 4 + g];
        float v0 = s[kt][g * 4 + 0] * 0.125f + bv4.x;
        float v1 = s[kt][g * 4 + 1] * 0.125f + bv4.y;
        float v2 = s[kt][g * 4 + 2] * 0.125f + bv4.z;
        float v3 = s[kt][g * 4 + 3] * 0.125f + bv4.w;
        s[kt][g * 4 + 0] = v0; s[kt][g * 4 + 1] = v1;
        s[kt][g * 4 + 2] = v2; s[kt][g * 4 + 3] = v3;
        mx[kt * 4 + g] = fmaxf(fmaxf(v0, v1), fmaxf(v2, v3));
      }
    mx[0] = fmaxf(mx[0], mx[4]); mx[1] = fmaxf(mx[1], mx[5]);
    mx[2] = fmaxf(mx[2], mx[6]); mx[3] = fmaxf(mx[3], mx[7]);
    float m = fmaxf(fmaxf(mx[0], mx[1]), fmaxf(mx[2], mx[3]));
    m = fmaxf(m, __shfl_xor(m, 32));

    // defer-max (T13)
    if (!__all(m <= mrow + 8.0f)) {
      float mnew = fmaxf(mrow, m);
      float corr = exp2_fast((mrow - mnew) * LOG2E);
      mrow = mnew;
      lrow *= corr;
#pragma unroll
      for (int dt = 0; dt < 2; dt++)
#pragma unroll
        for (int i = 0; i < 16; i++) o[dt][i] *= corr;
    }

    // exp2-form softmax + pack, pairwise sum tree
    float m2 = mrow * LOG2E;
    u32 c[2][8];
    float sm[8];
#pragma unroll
    for (int kt = 0; kt < 2; kt++)
#pragma unroll
      for (int g = 0; g < 4; g++) {
        float p0 = exp2_fast(__builtin_fmaf(s[kt][g * 4 + 0], LOG2E, -m2));
        float p1 = exp2_fast(__builtin_fmaf(s[kt][g * 4 + 1], LOG2E, -m2));
        float p2 = exp2_fast(__builtin_fmaf(s[kt][g * 4 + 2], LOG2E, -m2));
        float p3 = exp2_fast(__builtin_fmaf(s[kt][g * 4 + 3], LOG2E, -m2));
        sm[kt * 4 + g] = (p0 + p1) + (p2 + p3);
        c[kt][2 * g]     = cvt_pk_bf16(p0, p1);
        c[kt][2 * g + 1] = cvt_pk_bf16(p2, p3);
      }
    sm[0] += sm[4]; sm[1] += sm[5]; sm[2] += sm[6]; sm[3] += sm[7];
    float sum = (sm[0] + sm[1]) + (sm[2] + sm[3]);
    sum += __shfl_xor(sum, 32);
    lrow += sum;

    // staging + FULL bias prefetch for next tile (lands during PV)
    if (pf) {
      int kb = (tile + 1) * 64;
      kr0 = *(const uint4*)&Kbh[(kb + r0) * 64 + c8];
      kr1 = *(const uint4*)&Kbh[(kb + r0 + 32) * 64 + c8];
      vr0 = *(const uint4*)&Vtbh[r0 * 2048 + kb + c8];
      vr1 = *(const uint4*)&Vtbh[(r0 + 32) * 2048 + kb + c8];
#pragma unroll
      for (int kt = 0; kt < 2; kt++)
#pragma unroll
        for (int g = 0; g < 4; g++)
          bb[kt * 4 + g] = *(const float4*)&biasq[kb + kt * 32 + 8 * g + 4 * hi];
    }

    // PV: O^T[d][q] += Vt[d][k]·P^T[k][q]; partner exchange inline per kk
    __builtin_amdgcn_s_setprio(1);
#pragma unroll
    for (int kk = 0; kk < 4; kk++) {
      const int kt = kk >> 1, jA = 4 * (kk & 1);
      u32 d0 = (u32)__shfl_xor((int)c[kt][jA + 0], 32);
      u32 d1 = (u32)__shfl_xor((int)c[kt][jA + 1], 32);
      u32 d2 = (u32)__shfl_xor((int)c[kt][jA + 2], 32);
      u32 d3 = (u32)__shfl_xor((int)c[kt][jA + 3], 32);
      union { u32 u[4]; bf16x8 v; } pfg;
      pfg.u[0] = hi ? d2 : c[kt][jA + 0];
      pfg.u[1] = hi ? d3 : c[kt][jA + 1];
      pfg.u[2] = hi ? c[kt][jA + 2] : d0;
      pfg.u[3] = hi ? c[kt][jA + 3] : d1;
#pragma unroll
      for (int dt = 0; dt < 2; dt++) {
        bf16x8 va = *(const bf16x8*)&Vl[(dt * 32 + l31) * LDSS + kk * 16 + hi * 8];
        o[dt] = __builtin_amdgcn_mfma_f32_32x32x16_bf16(va, pfg.v, o[dt], 0, 0, 0);
      }
    }
    __builtin_amdgcn_s_setprio(0);
  }

  // ---- merge the two KV halves via LDS (staging buffers are dead) ----
  __syncthreads();
  float* olds = (float*)smem;                          // [4][32][64] f32 = 32 KB
  float2* mllds = (float2*)(smem + (4 * 32 * 64) * 2); // byte offset 32768, 2 KB

  if (g2 == 1) {
    mllds[ww * 64 + lane] = make_float2(mrow, lrow);
#pragma unroll
    for (int dt = 0; dt < 2; dt++)
#pragma unroll
      for (int i = 0; i < 16; i++)
        olds[(ww * 32 + dt * 16 + i) * 64 + lane] = o[dt][i];
  }
  __syncthreads();
  if (g2 == 0) {
    float2 ml = mllds[ww * 64 + lane];
    float M = fmaxf(mrow, ml.x);
    float w0 = exp2_fast((mrow - M) * LOG2E), w1 = exp2_fast((ml.x - M) * LOG2E);
    float linv = 1.0f / (lrow * w0 + ml.y * w1);
    float cw0 = w0 * linv, cw1 = w1 * linv;
    size_t obase = (size_t)(b * 2048 + qrow) * 512 + h * 64;
#pragma unroll
    for (int dt = 0; dt < 2; dt++)
#pragma unroll
      for (int g = 0; g < 4; g++) {
        float v0 = o[dt][4 * g + 0] * cw0 + olds[(ww * 32 + dt * 16 + 4 * g + 0) * 64 + lane] * cw1;
        float v1 = o[dt][4 * g + 1] * cw0 + olds[(ww * 32 + dt * 16 + 4 * g + 1) * 64 + lane] * cw1;
        float v2 = o[dt][4 * g + 2] * cw0 + olds[(ww * 32 + dt * 16 + 4 * g + 2) * 64 + lane] * cw1;
        float v3 = o[dt][4 * g + 3] * cw0 + olds[(ww * 32 + dt * 16 + 4 * g + 3) * 64 + lane] * cw1;
        uint2 pr;
        pr.x = cvt_pk_bf16(v0, v1);
        pr.y = cvt_pk_bf16(v2, v3);
        *(uint2*)&O[obase + dt * 32 + 8 * g + 4 * hi] = pr;
      }
  }
}

// ---------------- output projection: 64x64 tile, reg-prefetch ----------------
__global__ __launch_bounds__(256) void outproj_kernel(
    const u16* __restrict__ Ob, const u16* __restrict__ woT,
    const float* __restrict__ bo, float* __restrict__ out) {
  __shared__ u16 Alds[64 * LDSS];
  __shared__ u16 Blds[64 * LDSS];
  int m0 = blockIdx.y * 64;
  int n0 = blockIdx.x * 64;
  int tid = threadIdx.x;
  int lane = tid & 63, w = tid >> 6;
  int wm = w >> 1, wn = w & 1;
  int l15 = lane & 15, l4 = lane >> 4;

  int r0 = tid >> 3, c8 = (tid & 7) * 8;
  uint4 ar0 = *(const uint4*)&Ob[(m0 + r0) * 512 + c8];
  uint4 ar1 = *(const uint4*)&Ob[(m0 + r0 + 32) * 512 + c8];
  uint4 br0 = *(const uint4*)&woT[(n0 + r0) * 512 + c8];
  uint4 br1 = *(const uint4*)&woT[(n0 + r0 + 32) * 512 + c8];

  f32x4 acc[2][2] = {};
  for (int ks = 0; ks < 8; ks++) {
    __syncthreads();
    *(uint4*)&Alds[r0 * LDSS + c8]        = ar0;
    *(uint4*)&Alds[(r0 + 32) * LDSS + c8] = ar1;
    *(uint4*)&Blds[r0 * LDSS + c8]        = br0;
    *(uint4*)&Blds[(r0 + 32) * LDSS + c8] = br1;
    __syncthreads();
    if (ks < 7) {
      int k0 = (ks + 1) * 64;
      ar0 = *(const uint4*)&Ob[(m0 + r0) * 512 + k0 + c8];
      ar1 = *(const uint4*)&Ob[(m0 + r0 + 32) * 512 + k0 + c8];
      br0 = *(const uint4*)&woT[(n0 + r0) * 512 + k0 + c8];
      br1 = *(const uint4*)&woT[(n0 + r0 + 32) * 512 + k0 + c8];
    }
#pragma unroll
    for (int kk = 0; kk < 2; kk++) {
      bf16x8 a[2], bfr[2];
#pragma unroll
      for (int f = 0; f < 2; f++) {
        a[f] = *(const bf16x8*)&Alds[(wm * 32 + f * 16 + l15) * LDSS + kk * 32 + l4 * 8];
        bfr[f] = *(const bf16x8*)&Blds[(wn * 32 + f * 16 + l15) * LDSS + kk * 32 + l4 * 8];
      }
#pragma unroll
      for (int fm = 0; fm < 2; fm++)
#pragma unroll
        for (int fn = 0; fn < 2; fn++)
          acc[fm][fn] = __builtin_amdgcn_mfma_f32_16x16x32_bf16(a[fm], bfr[fn], acc[fm][fn], 0, 0, 0);
    }
  }
#pragma unroll
  for (int fm = 0; fm < 2; fm++)
#pragma unroll
    for (int fn = 0; fn < 2; fn++)
#pragma unroll
      for (int r = 0; r < 4; r++) {
        int row = wm * 32 + fm * 16 + l4 * 4 + r;
        int col = wn * 32 + fn * 16 + l15;
        out[(size_t)(m0 + row) * 512 + n0 + col] = acc[fm][fn][r] + bo[n0 + col];
      }
}

extern "C" void kernel_launch(void* const* d_in, const int* in_sizes, int n_in,
                              void* d_out, int out_size, void* d_ws, size_t ws_size,
                              hipStream_t stream) {
  const float* x    = (const float*)d_in[0];
  const float* bias = (const float*)d_in[1];
  const float* wq   = (const float*)d_in[2];
  const float* bq   = (const float*)d_in[3];
  const float* wk   = (const float*)d_in[4];
  const float* bk   = (const float*)d_in[5];
  const float* wv   = (const float*)d_in[6];
  const float* bv   = (const float*)d_in[7];
  const float* wo   = (const float*)d_in[8];
  const float* bo   = (const float*)d_in[9];
  float* out = (float*)d_out;

  char* ws = (char*)d_ws;
  u16* xb  = (u16*)(ws + 0);
  u16* wqT = (u16*)(ws + 8388608);
  u16* wkT = (u16*)(ws + 8912896);
  u16* wvT = (u16*)(ws + 9437184);
  u16* woT = (u16*)(ws + 9961472);
  u16* Qb  = (u16*)(ws + 10485760);
  u16* Kb  = (u16*)(ws + 18874368);
  u16* VtB = (u16*)(ws + 27262976);
  u16* Ob  = (u16*)(ws + 35651584);

  hipLaunchKernelGGL(cast_x_kernel, dim3(2048), dim3(256), 0, stream, x, xb);
  hipLaunchKernelGGL(cast_wT_kernel, dim3(8, 8, 4), dim3(256), 0, stream,
                     wq, wk, wv, wo, wqT, wkT, wvT, woT);
  hipLaunchKernelGGL(proj_kernel, dim3(8, 128, 3), dim3(256), 0, stream,
                     xb, wqT, wkT, wvT, bq, bk, bv, Qb, Kb, VtB);
  hipLaunchKernelGGL(attn_kernel, dim3(16, 8, 4), dim3(512), 0, stream,
                     Qb, Kb, VtB, bias, Ob);
  hipLaunchKernelGGL(outproj_kernel, dim3(8, 128), dim3(256), 0, stream,
                     Ob, woT, bo, out);
}

// Round 13
// 139.424 us; speedup vs baseline: 1.0970x; 1.0970x over previous
//
#include <hip/hip_runtime.h>
#include <hip/hip_bf16.h>

typedef __bf16 bf16x8 __attribute__((ext_vector_type(8)));
typedef float f32x4 __attribute__((ext_vector_type(4)));
typedef float f32x16 __attribute__((ext_vector_type(16)));
using u16 = unsigned short;
using u32 = unsigned int;

#define LDSS 72  // padded LDS row stride in bf16 elems

__device__ __forceinline__ u16 f2bf(float f) {
  union { float f; u32 u; } v; v.f = f;
  u32 r = v.u + 0x7fffu + ((v.u >> 16) & 1u);   // RNE
  return (u16)(r >> 16);
}

__device__ __forceinline__ u32 cvt_pk_bf16(float lo, float hi) {
  u32 r;
  asm("v_cvt_pk_bf16_f32 %0, %1, %2" : "=v"(r) : "v"(lo), "v"(hi));
  return r;
}

// ---------------- cast kernels ----------------
__global__ void cast_x_kernel(const float* __restrict__ x, u16* __restrict__ xb) {
  int i = (blockIdx.x * 256 + threadIdx.x) * 8;
  float4 f0 = *(const float4*)&x[i];
  float4 f1 = *(const float4*)&x[i + 4];
  u16 u[8];
  u[0] = f2bf(f0.x); u[1] = f2bf(f0.y); u[2] = f2bf(f0.z); u[3] = f2bf(f0.w);
  u[4] = f2bf(f1.x); u[5] = f2bf(f1.y); u[6] = f2bf(f1.z); u[7] = f2bf(f1.w);
  *(uint4*)&xb[i] = *(uint4*)u;
}

// weights (512x512, stored (in,out)) -> bf16 transposed (out,in), LDS-tiled.
__global__ __launch_bounds__(256) void cast_wT_kernel(
    const float* __restrict__ w0, const float* __restrict__ w1,
    const float* __restrict__ w2, const float* __restrict__ w3,
    u16* __restrict__ t0, u16* __restrict__ t1,
    u16* __restrict__ t2, u16* __restrict__ t3) {
  __shared__ u16 tl[64][72];
  int wi = blockIdx.z;
  const float* w; u16* t;
  if (wi == 0)      { w = w0; t = t0; }
  else if (wi == 1) { w = w1; t = t1; }
  else if (wi == 2) { w = w2; t = t2; }
  else              { w = w3; t = t3; }
  int r0 = blockIdx.x * 64, c0 = blockIdx.y * 64;
  int tid = threadIdx.x;
  int row = tid >> 2, q = tid & 3;
#pragma unroll
  for (int j = 0; j < 4; j++) {
    float4 f = *(const float4*)&w[(r0 + row) * 512 + c0 + q * 16 + j * 4];
    tl[row][q * 16 + j * 4 + 0] = f2bf(f.x);
    tl[row][q * 16 + j * 4 + 1] = f2bf(f.y);
    tl[row][q * 16 + j * 4 + 2] = f2bf(f.z);
    tl[row][q * 16 + j * 4 + 3] = f2bf(f.w);
  }
  __syncthreads();
  int crow = tid >> 2;
  u16 tmp[16];
#pragma unroll
  for (int j = 0; j < 16; j++) tmp[j] = tl[q * 16 + j][crow];
  *(uint4*)&t[(c0 + crow) * 512 + r0 + q * 16]     = *(uint4*)&tmp[0];
  *(uint4*)&t[(c0 + crow) * 512 + r0 + q * 16 + 8] = *(uint4*)&tmp[8];
}

// ---------------- QKV projection GEMM: 64x64 tile, reg-prefetch ----------------
__global__ __launch_bounds__(256) void proj_kernel(
    const u16* __restrict__ xb,
    const u16* __restrict__ wqT, const u16* __restrict__ wkT, const u16* __restrict__ wvT,
    const float* __restrict__ bq, const float* __restrict__ bk, const float* __restrict__ bv,
    u16* __restrict__ Q, u16* __restrict__ K, u16* __restrict__ Vt) {
  __shared__ u16 Alds[64 * LDSS];
  __shared__ u16 Blds[64 * LDSS];
  int which = blockIdx.z;
  const u16* wT; const float* bias; u16* out;
  if (which == 0)      { wT = wqT; bias = bq; out = Q; }
  else if (which == 1) { wT = wkT; bias = bk; out = K; }
  else                 { wT = wvT; bias = bv; out = Vt; }

  int m0 = blockIdx.y * 64;
  int n0 = blockIdx.x * 64;
  int tid = threadIdx.x;
  int lane = tid & 63, w = tid >> 6;
  int wm = w >> 1, wn = w & 1;
  int l15 = lane & 15, l4 = lane >> 4;

  int r0 = tid >> 3, c8 = (tid & 7) * 8;

  uint4 ar0 = *(const uint4*)&xb[(m0 + r0) * 512 + c8];
  uint4 ar1 = *(const uint4*)&xb[(m0 + r0 + 32) * 512 + c8];
  uint4 br0 = *(const uint4*)&wT[(n0 + r0) * 512 + c8];
  uint4 br1 = *(const uint4*)&wT[(n0 + r0 + 32) * 512 + c8];

  f32x4 acc[2][2] = {};
  for (int ks = 0; ks < 8; ks++) {
    __syncthreads();
    *(uint4*)&Alds[r0 * LDSS + c8]        = ar0;
    *(uint4*)&Alds[(r0 + 32) * LDSS + c8] = ar1;
    *(uint4*)&Blds[r0 * LDSS + c8]        = br0;
    *(uint4*)&Blds[(r0 + 32) * LDSS + c8] = br1;
    __syncthreads();
    if (ks < 7) {
      int k0 = (ks + 1) * 64;
      ar0 = *(const uint4*)&xb[(m0 + r0) * 512 + k0 + c8];
      ar1 = *(const uint4*)&xb[(m0 + r0 + 32) * 512 + k0 + c8];
      br0 = *(const uint4*)&wT[(n0 + r0) * 512 + k0 + c8];
      br1 = *(const uint4*)&wT[(n0 + r0 + 32) * 512 + k0 + c8];
    }
#pragma unroll
    for (int kk = 0; kk < 2; kk++) {
      bf16x8 a[2], b[2];
#pragma unroll
      for (int f = 0; f < 2; f++) {
        a[f] = *(const bf16x8*)&Alds[(wm * 32 + f * 16 + l15) * LDSS + kk * 32 + l4 * 8];
        b[f] = *(const bf16x8*)&Blds[(wn * 32 + f * 16 + l15) * LDSS + kk * 32 + l4 * 8];
      }
#pragma unroll
      for (int fm = 0; fm < 2; fm++)
#pragma unroll
        for (int fn = 0; fn < 2; fn++) {
          if (which == 2)
            acc[fm][fn] = __builtin_amdgcn_mfma_f32_16x16x32_bf16(b[fn], a[fm], acc[fm][fn], 0, 0, 0);
          else
            acc[fm][fn] = __builtin_amdgcn_mfma_f32_16x16x32_bf16(a[fm], b[fn], acc[fm][fn], 0, 0, 0);
        }
    }
  }
  int bidx = m0 >> 11;
  int head = n0 >> 6;
  if (which == 2) {
#pragma unroll
    for (int fm = 0; fm < 2; fm++)
#pragma unroll
      for (int fn = 0; fn < 2; fn++)
#pragma unroll
        for (int r = 0; r < 4; r++) {
          int drow = wn * 32 + fn * 16 + l4 * 4 + r;
          int col  = wm * 32 + fm * 16 + l15;
          float vv = acc[fm][fn][r] + bias[n0 + drow];
          out[((size_t)(bidx * 8 + head) * 64 + drow) * 2048 + (m0 & 2047) + col] = f2bf(vv);
        }
  } else {
#pragma unroll
    for (int fm = 0; fm < 2; fm++)
#pragma unroll
      for (int fn = 0; fn < 2; fn++)
#pragma unroll
        for (int r = 0; r < 4; r++) {
          int row = wm * 32 + fm * 16 + l4 * 4 + r;
          int col = wn * 32 + fn * 16 + l15;
          int nrow = (m0 & 2047) + row;
          float vv = acc[fm][fn][r] + bias[n0 + col];
          out[(((size_t)(bidx * 8 + head) * 2048) + nrow) * 64 + col] = f2bf(vv);
        }
  }
}

// ---------------- flash attention: r6 dataflow, 2 sub-tiles per barrier pair ----------------
// 4 waves x 32 q-rows = qtile 128; KVBLK=128 (2 x 64 sub-tiles); 16 barrier pairs.
__device__ __forceinline__ void attn_subiter(
    const u16* __restrict__ Kl, const u16* __restrict__ Vl,
    float4 bv0, float4 bv1, float4 bv2, float4 bv3,
    float4 bv4, float4 bv5, float4 bv6, float4 bv7,
    bf16x8 q0, bf16x8 q1, bf16x8 q2, bf16x8 q3,
    f32x16& o0, f32x16& o1, float& mrow, float& lrow,
    int l31, int hi) {
  bf16x8 qf[4] = {q0, q1, q2, q3};
  float4 bb[8] = {bv0, bv1, bv2, bv3, bv4, bv5, bv6, bv7};

  f32x16 s[2] = {};
  __builtin_amdgcn_s_setprio(1);
#pragma unroll
  for (int dk = 0; dk < 4; dk++) {
    bf16x8 a0 = *(const bf16x8*)&Kl[l31 * LDSS + dk * 16 + hi * 8];
    s[0] = __builtin_amdgcn_mfma_f32_32x32x16_bf16(a0, qf[dk], s[0], 0, 0, 0);
    bf16x8 a1 = *(const bf16x8*)&Kl[(32 + l31) * LDSS + dk * 16 + hi * 8];
    s[1] = __builtin_amdgcn_mfma_f32_32x32x16_bf16(a1, qf[dk], s[1], 0, 0, 0);
  }
  __builtin_amdgcn_s_setprio(0);

  float m = -1e30f;
#pragma unroll
  for (int kt = 0; kt < 2; kt++)
#pragma unroll
    for (int g = 0; g < 4; g++) {
      float4 bv4_ = bb[kt * 4 + g];
#pragma unroll
      for (int j = 0; j < 4; j++) {
        float val = s[kt][g * 4 + j] * 0.125f + ((const float*)&bv4_)[j];
        s[kt][g * 4 + j] = val;
        m = fmaxf(m, val);
      }
    }
  m = fmaxf(m, __shfl_xor(m, 32));

  if (!__all(m <= mrow + 8.0f)) {
    float mnew = fmaxf(mrow, m);
    float corr = __expf(mrow - mnew);
    mrow = mnew;
    lrow *= corr;
#pragma unroll
    for (int i = 0; i < 16; i++) { o0[i] *= corr; o1[i] *= corr; }
  }

  u32 c[2][8];
  float sum = 0.f;
#pragma unroll
  for (int kt = 0; kt < 2; kt++)
#pragma unroll
    for (int g = 0; g < 4; g++) {
      float p0 = __expf(s[kt][g * 4 + 0] - mrow);
      float p1 = __expf(s[kt][g * 4 + 1] - mrow);
      float p2 = __expf(s[kt][g * 4 + 2] - mrow);
      float p3 = __expf(s[kt][g * 4 + 3] - mrow);
      sum += (p0 + p1) + (p2 + p3);
      c[kt][2 * g]     = cvt_pk_bf16(p0, p1);
      c[kt][2 * g + 1] = cvt_pk_bf16(p2, p3);
    }
  sum += __shfl_xor(sum, 32);
  lrow += sum;

  u32 dx[2][8];
#pragma unroll
  for (int kt = 0; kt < 2; kt++)
#pragma unroll
    for (int j = 0; j < 8; j++)
      dx[kt][j] = (u32)__shfl_xor((int)c[kt][j], 32);

  __builtin_amdgcn_s_setprio(1);
#pragma unroll
  for (int kk = 0; kk < 4; kk++) {
    const int kt = kk >> 1, jA = 4 * (kk & 1);
    union { u32 u[4]; bf16x8 v; } pfg;
    pfg.u[0] = hi ? dx[kt][jA + 2] : c[kt][jA];
    pfg.u[1] = hi ? dx[kt][jA + 3] : c[kt][jA + 1];
    pfg.u[2] = hi ? c[kt][jA + 2]  : dx[kt][jA];
    pfg.u[3] = hi ? c[kt][jA + 3]  : dx[kt][jA + 1];
    bf16x8 va0 = *(const bf16x8*)&Vl[l31 * LDSS + kk * 16 + hi * 8];
    o0 = __builtin_amdgcn_mfma_f32_32x32x16_bf16(va0, pfg.v, o0, 0, 0, 0);
    bf16x8 va1 = *(const bf16x8*)&Vl[(32 + l31) * LDSS + kk * 16 + hi * 8];
    o1 = __builtin_amdgcn_mfma_f32_32x32x16_bf16(va1, pfg.v, o1, 0, 0, 0);
  }
  __builtin_amdgcn_s_setprio(0);
}

__global__ __launch_bounds__(256, 2) void attn_kernel(
    const u16* __restrict__ Q, const u16* __restrict__ K, const u16* __restrict__ Vt,
    const float* __restrict__ bias, u16* __restrict__ O) {
  __shared__ u16 Klds[2][64 * LDSS];
  __shared__ u16 Vtlds[2][64 * LDSS];

  int qt = blockIdx.x, h = blockIdx.y, b = blockIdx.z;
  int tid = threadIdx.x;
  int lane = tid & 63, w = tid >> 6;
  int l31 = lane & 31, hi = lane >> 5;
  int qrow = qt * 128 + w * 32 + l31;

  const u16* Qbh  = Q  + (size_t)(b * 8 + h) * 2048 * 64;
  const u16* Kbh  = K  + (size_t)(b * 8 + h) * 2048 * 64;
  const u16* Vtbh = Vt + (size_t)(b * 8 + h) * 64 * 2048;
  const float* biasq = bias + (size_t)b * 2048 * 2048 + (size_t)qrow * 2048;

  bf16x8 qf0 = *(const bf16x8*)&Qbh[qrow * 64 + 0 * 16 + hi * 8];
  bf16x8 qf1 = *(const bf16x8*)&Qbh[qrow * 64 + 1 * 16 + hi * 8];
  bf16x8 qf2 = *(const bf16x8*)&Qbh[qrow * 64 + 2 * 16 + hi * 8];
  bf16x8 qf3 = *(const bf16x8*)&Qbh[qrow * 64 + 3 * 16 + hi * 8];

  f32x16 o0 = {}, o1 = {};
  float mrow = -1e30f, lrow = 0.f;

  int r0 = tid >> 3, c8 = (tid & 7) * 8;

  // prologue: stage regs for tile 0 (both 64-row sub-tiles) + bias sub0
  uint4 kr00 = *(const uint4*)&Kbh[(r0     ) * 64 + c8];
  uint4 kr01 = *(const uint4*)&Kbh[(r0 + 32) * 64 + c8];
  uint4 kr10 = *(const uint4*)&Kbh[(64 + r0     ) * 64 + c8];
  uint4 kr11 = *(const uint4*)&Kbh[(64 + r0 + 32) * 64 + c8];
  uint4 vr00 = *(const uint4*)&Vtbh[(r0     ) * 2048 + c8];
  uint4 vr01 = *(const uint4*)&Vtbh[(r0 + 32) * 2048 + c8];
  uint4 vr10 = *(const uint4*)&Vtbh[(r0     ) * 2048 + 64 + c8];
  uint4 vr11 = *(const uint4*)&Vtbh[(r0 + 32) * 2048 + 64 + c8];

  float4 bA0 = *(const float4*)&biasq[0 * 32 + 8 * 0 + 4 * hi];
  float4 bA1 = *(const float4*)&biasq[0 * 32 + 8 * 1 + 4 * hi];
  float4 bA2 = *(const float4*)&biasq[0 * 32 + 8 * 2 + 4 * hi];
  float4 bA3 = *(const float4*)&biasq[0 * 32 + 8 * 3 + 4 * hi];
  float4 bA4 = *(const float4*)&biasq[1 * 32 + 8 * 0 + 4 * hi];
  float4 bA5 = *(const float4*)&biasq[1 * 32 + 8 * 1 + 4 * hi];
  float4 bA6 = *(const float4*)&biasq[1 * 32 + 8 * 2 + 4 * hi];
  float4 bA7 = *(const float4*)&biasq[1 * 32 + 8 * 3 + 4 * hi];

  for (int tt = 0; tt < 16; tt++) {
    __syncthreads();   // (A) prev compute done; LDS safe
    *(uint4*)&Klds[0][(r0     ) * LDSS + c8] = kr00;
    *(uint4*)&Klds[0][(r0 + 32) * LDSS + c8] = kr01;
    *(uint4*)&Klds[1][(r0     ) * LDSS + c8] = kr10;
    *(uint4*)&Klds[1][(r0 + 32) * LDSS + c8] = kr11;
    *(uint4*)&Vtlds[0][(r0     ) * LDSS + c8] = vr00;
    *(uint4*)&Vtlds[0][(r0 + 32) * LDSS + c8] = vr01;
    *(uint4*)&Vtlds[1][(r0     ) * LDSS + c8] = vr10;
    *(uint4*)&Vtlds[1][(r0 + 32) * LDSS + c8] = vr11;
    __syncthreads();   // (B) staging visible

    bool pf = (tt < 15);
    if (pf) {
      int kb = (tt + 1) * 128;
      kr00 = *(const uint4*)&Kbh[(kb + r0     ) * 64 + c8];
      kr01 = *(const uint4*)&Kbh[(kb + r0 + 32) * 64 + c8];
      kr10 = *(const uint4*)&Kbh[(kb + 64 + r0     ) * 64 + c8];
      kr11 = *(const uint4*)&Kbh[(kb + 64 + r0 + 32) * 64 + c8];
      vr00 = *(const uint4*)&Vtbh[(r0     ) * 2048 + kb + c8];
      vr01 = *(const uint4*)&Vtbh[(r0 + 32) * 2048 + kb + c8];
      vr10 = *(const uint4*)&Vtbh[(r0     ) * 2048 + kb + 64 + c8];
      vr11 = *(const uint4*)&Vtbh[(r0 + 32) * 2048 + kb + 64 + c8];
    }

    // bias for sub-tile 1 of THIS tile (lands during sub0 compute)
    int s1b = tt * 128 + 64;
    float4 bB0 = *(const float4*)&biasq[s1b + 0 * 32 + 8 * 0 + 4 * hi];
    float4 bB1 = *(const float4*)&biasq[s1b + 0 * 32 + 8 * 1 + 4 * hi];
    float4 bB2 = *(const float4*)&biasq[s1b + 0 * 32 + 8 * 2 + 4 * hi];
    float4 bB3 = *(const float4*)&biasq[s1b + 0 * 32 + 8 * 3 + 4 * hi];
    float4 bB4 = *(const float4*)&biasq[s1b + 1 * 32 + 8 * 0 + 4 * hi];
    float4 bB5 = *(const float4*)&biasq[s1b + 1 * 32 + 8 * 1 + 4 * hi];
    float4 bB6 = *(const float4*)&biasq[s1b + 1 * 32 + 8 * 2 + 4 * hi];
    float4 bB7 = *(const float4*)&biasq[s1b + 1 * 32 + 8 * 3 + 4 * hi];

    attn_subiter(Klds[0], Vtlds[0], bA0, bA1, bA2, bA3, bA4, bA5, bA6, bA7,
                 qf0, qf1, qf2, qf3, o0, o1, mrow, lrow, l31, hi);

    if (pf) {
      int s0b = (tt + 1) * 128;
      bA0 = *(const float4*)&biasq[s0b + 0 * 32 + 8 * 0 + 4 * hi];
      bA1 = *(const float4*)&biasq[s0b + 0 * 32 + 8 * 1 + 4 * hi];
      bA2 = *(const float4*)&biasq[s0b + 0 * 32 + 8 * 2 + 4 * hi];
      bA3 = *(const float4*)&biasq[s0b + 0 * 32 + 8 * 3 + 4 * hi];
      bA4 = *(const float4*)&biasq[s0b + 1 * 32 + 8 * 0 + 4 * hi];
      bA5 = *(const float4*)&biasq[s0b + 1 * 32 + 8 * 1 + 4 * hi];
      bA6 = *(const float4*)&biasq[s0b + 1 * 32 + 8 * 2 + 4 * hi];
      bA7 = *(const float4*)&biasq[s0b + 1 * 32 + 8 * 3 + 4 * hi];
    }

    attn_subiter(Klds[1], Vtlds[1], bB0, bB1, bB2, bB3, bB4, bB5, bB6, bB7,
                 qf0, qf1, qf2, qf3, o0, o1, mrow, lrow, l31, hi);
  }

  float inv = 1.0f / lrow;
  size_t obase = (size_t)(b * 2048 + qrow) * 512 + h * 64;
#pragma unroll
  for (int g = 0; g < 4; g++) {
    uint2 pr;
    pr.x = cvt_pk_bf16(o0[4 * g + 0] * inv, o0[4 * g + 1] * inv);
    pr.y = cvt_pk_bf16(o0[4 * g + 2] * inv, o0[4 * g + 3] * inv);
    *(uint2*)&O[obase + 8 * g + 4 * hi] = pr;
  }
#pragma unroll
  for (int g = 0; g < 4; g++) {
    uint2 pr;
    pr.x = cvt_pk_bf16(o1[4 * g + 0] * inv, o1[4 * g + 1] * inv);
    pr.y = cvt_pk_bf16(o1[4 * g + 2] * inv, o1[4 * g + 3] * inv);
    *(uint2*)&O[obase + 32 + 8 * g + 4 * hi] = pr;
  }
}

// ---------------- output projection: 64x64 tile, reg-prefetch ----------------
__global__ __launch_bounds__(256) void outproj_kernel(
    const u16* __restrict__ Ob, const u16* __restrict__ woT,
    const float* __restrict__ bo, float* __restrict__ out) {
  __shared__ u16 Alds[64 * LDSS];
  __shared__ u16 Blds[64 * LDSS];
  int m0 = blockIdx.y * 64;
  int n0 = blockIdx.x * 64;
  int tid = threadIdx.x;
  int lane = tid & 63, w = tid >> 6;
  int wm = w >> 1, wn = w & 1;
  int l15 = lane & 15, l4 = lane >> 4;

  int r0 = tid >> 3, c8 = (tid & 7) * 8;
  uint4 ar0 = *(const uint4*)&Ob[(m0 + r0) * 512 + c8];
  uint4 ar1 = *(const uint4*)&Ob[(m0 + r0 + 32) * 512 + c8];
  uint4 br0 = *(const uint4*)&woT[(n0 + r0) * 512 + c8];
  uint4 br1 = *(const uint4*)&woT[(n0 + r0 + 32) * 512 + c8];

  f32x4 acc[2][2] = {};
  for (int ks = 0; ks < 8; ks++) {
    __syncthreads();
    *(uint4*)&Alds[r0 * LDSS + c8]        = ar0;
    *(uint4*)&Alds[(r0 + 32) * LDSS + c8] = ar1;
    *(uint4*)&Blds[r0 * LDSS + c8]        = br0;
    *(uint4*)&Blds[(r0 + 32) * LDSS + c8] = br1;
    __syncthreads();
    if (ks < 7) {
      int k0 = (ks + 1) * 64;
      ar0 = *(const uint4*)&Ob[(m0 + r0) * 512 + k0 + c8];
      ar1 = *(const uint4*)&Ob[(m0 + r0 + 32) * 512 + k0 + c8];
      br0 = *(const uint4*)&woT[(n0 + r0) * 512 + k0 + c8];
      br1 = *(const uint4*)&woT[(n0 + r0 + 32) * 512 + k0 + c8];
    }
#pragma unroll
    for (int kk = 0; kk < 2; kk++) {
      bf16x8 a[2], bfr[2];
#pragma unroll
      for (int f = 0; f < 2; f++) {
        a[f] = *(const bf16x8*)&Alds[(wm * 32 + f * 16 + l15) * LDSS + kk * 32 + l4 * 8];
        bfr[f] = *(const bf16x8*)&Blds[(wn * 32 + f * 16 + l15) * LDSS + kk * 32 + l4 * 8];
      }
#pragma unroll
      for (int fm = 0; fm < 2; fm++)
#pragma unroll
        for (int fn = 0; fn < 2; fn++)
          acc[fm][fn] = __builtin_amdgcn_mfma_f32_16x16x32_bf16(a[fm], bfr[fn], acc[fm][fn], 0, 0, 0);
    }
  }
#pragma unroll
  for (int fm = 0; fm < 2; fm++)
#pragma unroll
    for (int fn = 0; fn < 2; fn++)
#pragma unroll
      for (int r = 0; r < 4; r++) {
        int row = wm * 32 + fm * 16 + l4 * 4 + r;
        int col = wn * 32 + fn * 16 + l15;
        out[(size_t)(m0 + row) * 512 + n0 + col] = acc[fm][fn][r] + bo[n0 + col];
      }
}

extern "C" void kernel_launch(void* const* d_in, const int* in_sizes, int n_in,
                              void* d_out, int out_size, void* d_ws, size_t ws_size,
                              hipStream_t stream) {
  const float* x    = (const float*)d_in[0];
  const float* bias = (const float*)d_in[1];
  const float* wq   = (const float*)d_in[2];
  const float* bq   = (const float*)d_in[3];
  const float* wk   = (const float*)d_in[4];
  const float* bk   = (const float*)d_in[5];
  const float* wv   = (const float*)d_in[6];
  const float* bv   = (const float*)d_in[7];
  const float* wo   = (const float*)d_in[8];
  const float* bo   = (const float*)d_in[9];
  float* out = (float*)d_out;

  char* ws = (char*)d_ws;
  u16* xb  = (u16*)(ws + 0);
  u16* wqT = (u16*)(ws + 8388608);
  u16* wkT = (u16*)(ws + 8912896);
  u16* wvT = (u16*)(ws + 9437184);
  u16* woT = (u16*)(ws + 9961472);
  u16* Qb  = (u16*)(ws + 10485760);
  u16* Kb  = (u16*)(ws + 18874368);
  u16* VtB = (u16*)(ws + 27262976);
  u16* Ob  = (u16*)(ws + 35651584);

  hipLaunchKernelGGL(cast_x_kernel, dim3(2048), dim3(256), 0, stream, x, xb);
  hipLaunchKernelGGL(cast_wT_kernel, dim3(8, 8, 4), dim3(256), 0, stream,
                     wq, wk, wv, wo, wqT, wkT, wvT, woT);
  hipLaunchKernelGGL(proj_kernel, dim3(8, 128, 3), dim3(256), 0, stream,
                     xb, wqT, wkT, wvT, bq, bk, bv, Qb, Kb, VtB);
  hipLaunchKernelGGL(attn_kernel, dim3(16, 8, 4), dim3(256), 0, stream,
                     Qb, Kb, VtB, bias, Ob);
  hipLaunchKernelGGL(outproj_kernel, dim3(8, 128), dim3(256), 0, stream,
                     Ob, woT, bo, out);
}